// Round 1
// baseline (3228.885 us; speedup 1.0000x reference)
//
#include <hip/hip_runtime.h>
#include <hip/hip_bf16.h>
#include <math.h>

#define B_ 4
#define CG_ 64
#define H_ 240
#define W_ 1216
#define TW_ 128
#define LW_ (TW_ + 2)

// Bilinear sample with zero padding, per-corner validity (matches mmcv/ref).
__device__ __forceinline__ float bilin_zero(const float* __restrict__ img, float y, float x) {
    float y0f = floorf(y), x0f = floorf(x);
    float wy = y - y0f, wx = x - x0f;
    int y0 = (int)y0f, x0 = (int)x0f;
    int y1 = y0 + 1, x1 = x0 + 1;
    bool yv0 = ((unsigned)y0 < (unsigned)H_);
    bool yv1 = ((unsigned)y1 < (unsigned)H_);
    bool xv0 = ((unsigned)x0 < (unsigned)W_);
    bool xv1 = ((unsigned)x1 < (unsigned)W_);
    float v00 = (yv0 && xv0) ? img[y0 * W_ + x0] : 0.f;
    float v01 = (yv0 && xv1) ? img[y0 * W_ + x1] : 0.f;
    float v10 = (yv1 && xv0) ? img[y1 * W_ + x0] : 0.f;
    float v11 = (yv1 && xv1) ? img[y1 * W_ + x1] : 0.f;
    return v00 * (1.f - wy) * (1.f - wx) + v01 * (1.f - wy) * wx
         + v10 * wy * (1.f - wx) + v11 * wy * wx;
}

// Fused: 3x3 conv (Cg=64 -> 24) + offset/affinity prep + initial blend.
// One block = one output row-tile of TW_ pixels. Guidance tile staged in LDS as bf16.
__global__ __launch_bounds__(128) void conv_prep_kernel(
    const float* __restrict__ guidance, const float* __restrict__ conv_w,
    const float* __restrict__ conv_b, const float* __restrict__ confidence,
    const float* __restrict__ feat_init, const float* __restrict__ feat_fix,
    const float* __restrict__ aff_scale,
    float* __restrict__ out_offset,   // [B][18][H][W]
    float* __restrict__ out_aff9,     // [B][9][H][W]
    float* __restrict__ fb0)          // [B][H][W] blended feat for iter 0
{
    __shared__ __hip_bfloat16 gl[CG_ * 3 * LW_];   // [c][ky][col] : ~50 KB

    const int tid = threadIdx.x;
    const int w0 = blockIdx.x * TW_;
    const int h = blockIdx.y;
    const int b = blockIdx.z;

    // ---- stage guidance rows h-1..h+1, cols w0-1..w0+TW_ ----
    const int total = CG_ * 3 * LW_;
    for (int i = tid; i < total; i += 128) {
        int col = i % LW_;
        int rc = i / LW_;
        int ky = rc % 3;
        int c = rc / 3;
        int gw = w0 - 1 + col;
        int gh = h - 1 + ky;
        float v = 0.f;
        if (gh >= 0 && gh < H_ && gw >= 0 && gw < W_)
            v = guidance[((b * CG_ + c) * H_ + gh) * W_ + gw];
        gl[(c * 3 + ky) * LW_ + col] = __float2bfloat16(v);
    }
    __syncthreads();

    const int w = w0 + tid;
    if (w >= W_) return;

    // ---- conv: 24 output channels for this pixel ----
    float acc[24];
#pragma unroll
    for (int n = 0; n < 24; n++) acc[n] = conv_b[n];

    for (int c = 0; c < CG_; c++) {
#pragma unroll
        for (int ky = 0; ky < 3; ky++) {
            const __hip_bfloat16* row = &gl[(c * 3 + ky) * LW_ + tid];
            float g0 = __bfloat162float(row[0]);
            float g1 = __bfloat162float(row[1]);
            float g2 = __bfloat162float(row[2]);
            const float* wp = conv_w + (c * 9 + ky * 3);   // uniform -> scalar loads
#pragma unroll
            for (int n = 0; n < 24; n++) {
                const float* wn = wp + n * 576;
                acc[n] += wn[0] * g0 + wn[1] * g1 + wn[2] * g2;
            }
        }
    }

    // ---- prep: offsets, affinities ----
    const float scale = aff_scale[0] + 1e-8f;
    const float* confb = confidence + (size_t)b * H_ * W_;

    float dyv[8], dxv[8], av[8];
    float s = 0.f;
#pragma unroll
    for (int j = 0; j < 8; j++) {
        float dy = acc[j];
        float dx = acc[8 + j];
        float a = tanhf(acc[16 + j]) / scale;
        float conf = bilin_zero(confb, (float)h + dy, (float)w + dx);
        a *= conf;
        dyv[j] = dy; dxv[j] = dx; av[j] = a;
        s += fabsf(a);
    }
    s = fmaxf(s + 1e-4f, 1.0f);
    float inv_s = 1.0f / s;
    float suma = 0.f;
#pragma unroll
    for (int j = 0; j < 8; j++) { av[j] *= inv_s; suma += av[j]; }
    const float aref = 1.0f - suma;

    const int hw = h * W_ + w;
#pragma unroll
    for (int k = 0; k < 9; k++) {
        float dy = (k == 4) ? 0.f : dyv[(k < 4) ? k : k - 1];
        float dx = (k == 4) ? 0.f : dxv[(k < 4) ? k : k - 1];
        float a  = (k == 4) ? aref : av[(k < 4) ? k : k - 1];
        out_offset[((size_t)(b * 18 + 2 * k) * H_) * W_ + hw] = dy;
        out_offset[((size_t)(b * 18 + 2 * k + 1) * H_) * W_ + hw] = dx;
        out_aff9[((size_t)(b * 9 + k) * H_) * W_ + hw] = a;
    }

    // ---- initial blended feat ----
    const size_t pix = (size_t)b * H_ * W_ + hw;
    float ff = feat_fix[pix];
    float fi = feat_init[pix];
    float m = (ff > 0.f) ? 1.f : 0.f;
    fb0[pix] = (1.f - m) * fi + m * ff;
}

// One propagation step. do_blend=1 for iters 0..4 (applies mask blend for the
// NEXT iteration's input), 0 for the final iteration (raw sum -> d_out).
__global__ __launch_bounds__(256) void prop_kernel(
    const float* __restrict__ fb_in, const float* __restrict__ offset,
    const float* __restrict__ aff9, const float* __restrict__ feat_fix,
    float* __restrict__ out, int do_blend)
{
    const int idx = blockIdx.x * 256 + threadIdx.x;
    const int n = B_ * H_ * W_;
    if (idx >= n) return;
    const int w = idx % W_;
    const int h = (idx / W_) % H_;
    const int b = idx / (W_ * H_);
    const float* fbb = fb_in + (size_t)b * H_ * W_;
    const int hw = h * W_ + w;

    float sum = 0.f;
#pragma unroll
    for (int k = 0; k < 9; k++) {
        float dy = offset[((size_t)(b * 18 + 2 * k) * H_) * W_ + hw];
        float dx = offset[((size_t)(b * 18 + 2 * k + 1) * H_) * W_ + hw];
        float a  = aff9[((size_t)(b * 9 + k) * H_) * W_ + hw];
        float y = (float)h + (float)(k / 3 - 1) + dy;
        float x = (float)w + (float)(k % 3 - 1) + dx;
        sum += a * bilin_zero(fbb, y, x);
    }
    if (do_blend) {
        float ff = feat_fix[idx];
        float m = (ff > 0.f) ? 1.f : 0.f;
        sum = (1.f - m) * sum + m * ff;
    }
    out[idx] = sum;
}

extern "C" void kernel_launch(void* const* d_in, const int* in_sizes, int n_in,
                              void* d_out, int out_size, void* d_ws, size_t ws_size,
                              hipStream_t stream) {
    const float* feat_init  = (const float*)d_in[0];
    const float* guidance   = (const float*)d_in[1];
    const float* confidence = (const float*)d_in[2];
    const float* feat_fix   = (const float*)d_in[3];
    const float* conv_w     = (const float*)d_in[4];
    const float* conv_b     = (const float*)d_in[5];
    const float* aff_scale  = (const float*)d_in[6];

    float* out_feat = (float*)d_out;                       // [B][1][H][W]
    const size_t P1 = (size_t)B_ * H_ * W_;
    float* out_offset = out_feat + P1;                     // [B][18][H][W]
    float* out_aff9   = out_offset + 18 * P1;              // [B][9][H][W]

    float* fb0 = (float*)d_ws;
    float* fb1 = fb0 + P1;

    dim3 cgrid((W_ + TW_ - 1) / TW_, H_, B_);
    conv_prep_kernel<<<cgrid, 128, 0, stream>>>(
        guidance, conv_w, conv_b, confidence, feat_init, feat_fix, aff_scale,
        out_offset, out_aff9, fb0);

    const int n = B_ * H_ * W_;
    const int pblocks = (n + 255) / 256;
    float* bufs[2] = {fb0, fb1};
    for (int it = 0; it < 6; it++) {
        const float* in = bufs[it & 1];
        float* o = (it == 5) ? out_feat : bufs[(it + 1) & 1];
        prop_kernel<<<pblocks, 256, 0, stream>>>(
            in, out_offset, out_aff9, feat_fix, o, (it < 5) ? 1 : 0);
    }
}

// Round 2
// 1190.462 us; speedup vs baseline: 2.7123x; 2.7123x over previous
//
#include <hip/hip_runtime.h>
#include <hip/hip_bf16.h>
#include <math.h>

#define B_ 4
#define CG_ 64
#define H_ 240
#define W_ 1216
#define NUMK 576           // 9 taps * 64 ch
#define TW 128             // output pixels per block (along W)
#define LW (TW + 2)        // staged cols incl. halo
#define CPAD 72            // channel stride in LDS (64 + 8 pad) -> 144 B rows, conflict-free b128
#define NWT 10             // ceil(1216/128)
#define NBLK (NWT * H_ * B_)   // 9600 blocks, %8==0 -> bijective XCD swizzle
#define CBS 132            // epilogue cbuf pixel stride (f32)

typedef __attribute__((ext_vector_type(8))) short bf16x8;
typedef __attribute__((ext_vector_type(4))) float f32x4;

// Bilinear sample with zero padding, per-corner validity (matches mmcv/ref).
__device__ __forceinline__ float bilin_zero(const float* __restrict__ img, float y, float x) {
    float y0f = floorf(y), x0f = floorf(x);
    float wy = y - y0f, wx = x - x0f;
    int y0 = (int)y0f, x0 = (int)x0f;
    int y1 = y0 + 1, x1 = x0 + 1;
    bool yv0 = ((unsigned)y0 < (unsigned)H_);
    bool yv1 = ((unsigned)y1 < (unsigned)H_);
    bool xv0 = ((unsigned)x0 < (unsigned)W_);
    bool xv1 = ((unsigned)x1 < (unsigned)W_);
    float v00 = (yv0 && xv0) ? img[y0 * W_ + x0] : 0.f;
    float v01 = (yv0 && xv1) ? img[y0 * W_ + x1] : 0.f;
    float v10 = (yv1 && xv0) ? img[y1 * W_ + x0] : 0.f;
    float v11 = (yv1 && xv1) ? img[y1 * W_ + x1] : 0.f;
    return v00 * (1.f - wy) * (1.f - wx) + v01 * (1.f - wy) * wx
         + v10 * wy * (1.f - wx) + v11 * wy * wx;
}

// Repack conv_w [24][64][3][3] (k = c*9+tap) -> wbf [32][576] bf16 with k' = tap*64+c.
// Rows 24..31 zero (M padded to 32 for two 16-row MFMA tiles).
__global__ __launch_bounds__(256) void repack_w_kernel(
    const float* __restrict__ conv_w, __hip_bfloat16* __restrict__ wbf)
{
    int i = blockIdx.x * 256 + threadIdx.x;
    if (i >= 32 * NUMK) return;
    int m = i / NUMK, k = i % NUMK;
    int tap = k / 64, c = k % 64;
    float v = (m < 24) ? conv_w[m * NUMK + c * 9 + tap] : 0.f;
    wbf[i] = __float2bfloat16(v);
}

// Implicit-GEMM conv (MFMA bf16) + offset/affinity prep + initial blend.
__global__ __launch_bounds__(256, 2) void conv_mfma_kernel(
    const float* __restrict__ guidance, const __hip_bfloat16* __restrict__ wbf,
    const float* __restrict__ conv_b, const float* __restrict__ confidence,
    const float* __restrict__ feat_init, const float* __restrict__ feat_fix,
    const float* __restrict__ aff_scale,
    float* __restrict__ out_offset,   // [B][18][H][W]
    float* __restrict__ out_aff9,     // [B][9][H][W]
    float* __restrict__ fb0)          // [B][H][W]
{
    __shared__ __hip_bfloat16 gl[3 * LW * CPAD];   // [ky][col][c], 56160 B; reused as cbuf

    const int tid = threadIdx.x;

    // XCD-bijective swizzle, h-fastest within each XCD chunk (guidance row reuse in L2).
    int lin = (blockIdx.x % 8) * (NBLK / 8) + blockIdx.x / 8;
    const int h  = lin % H_;
    const int t  = lin / H_;
    const int wt = t % NWT;
    const int b  = t / NWT;
    const int w0 = wt * TW;

    // ---- stage guidance rows h-1..h+1, cols w0-1..w0+TW, all 64 ch, as bf16 ----
    // i = (ky*16 + c4)*LW + col ; thread loads 4 channels (c4*4..+3), writes one b64.
    for (int i = tid; i < 3 * 16 * LW; i += 256) {
        int col = i % LW;
        int rc = i / LW;
        int ky = rc % 3;     // note: c4 outer so consecutive i -> consecutive col (coalesced)
        int c4 = rc / 3;
        int gh = h - 1 + ky;
        int gw = w0 - 1 + col;
        bool vok = (gh >= 0) & (gh < H_) & (gw >= 0) & (gw < W_);
        union { unsigned long long u; __hip_bfloat16 hv[4]; } pk;
        #pragma unroll
        for (int j = 0; j < 4; j++) {
            int c = c4 * 4 + j;
            float v = vok ? guidance[(((size_t)b * CG_ + c) * H_ + gh) * W_ + gw] : 0.f;
            pk.hv[j] = __float2bfloat16(v);
        }
        *(unsigned long long*)&gl[(size_t)(ky * LW + col) * CPAD + c4 * 4] = pk.u;
    }
    __syncthreads();

    // ---- MFMA K-loop: K = 576 = 18 steps of 32. k' = tap*64 + c. ----
    const int lane = tid & 63;
    const int wid  = tid >> 6;       // wave 0..3, handles pixels wid*32..wid*32+31
    const int p    = lane & 15;
    const int g    = lane >> 4;

    f32x4 acc[2][2] = {};            // [Mtile][Ntile]

    for (int s = 0; s < 18; s++) {
        int tap = s >> 1;
        int ky = tap / 3, kx = tap % 3;
        int c0 = (s & 1) * 32;
        const __hip_bfloat16* wp = wbf + s * 32 + g * 8;
        bf16x8 a0 = *(const bf16x8*)(wp + (size_t)p * NUMK);
        bf16x8 a1 = *(const bf16x8*)(wp + (size_t)(16 + p) * NUMK);
        const __hip_bfloat16* lbase = gl + (size_t)(ky * LW) * CPAD + c0 + g * 8;
        int colbase = wid * 32 + kx;
        bf16x8 b0 = *(const bf16x8*)(lbase + (size_t)(colbase + p) * CPAD);
        bf16x8 b1 = *(const bf16x8*)(lbase + (size_t)(colbase + 16 + p) * CPAD);
        acc[0][0] = __builtin_amdgcn_mfma_f32_16x16x32_bf16(a0, b0, acc[0][0], 0, 0, 0);
        acc[1][0] = __builtin_amdgcn_mfma_f32_16x16x32_bf16(a1, b0, acc[1][0], 0, 0, 0);
        acc[0][1] = __builtin_amdgcn_mfma_f32_16x16x32_bf16(a0, b1, acc[0][1], 0, 0, 0);
        acc[1][1] = __builtin_amdgcn_mfma_f32_16x16x32_bf16(a1, b1, acc[1][1], 0, 0, 0);
    }
    __syncthreads();   // all waves done reading gl

    // ---- spill conv result to LDS: cbuf[ch][px], ch<24, px<TW ----
    float* cbuf = (float*)gl;
    #pragma unroll
    for (int mt = 0; mt < 2; mt++) {
        int ch = mt * 16 + g * 4;
        if (ch < 24) {
            #pragma unroll
            for (int nt = 0; nt < 2; nt++) {
                int px = wid * 32 + nt * 16 + p;
                #pragma unroll
                for (int r = 0; r < 4; r++)
                    cbuf[(size_t)(ch + r) * CBS + px] = acc[mt][nt][r];
            }
        }
    }
    __syncthreads();

    // ---- prep: offsets, affinities, initial blend (threads 0..127 = pixels) ----
    if (tid < TW) {
        const int w = w0 + tid;
        if (w < W_) {
            float a24[24];
            #pragma unroll
            for (int ch = 0; ch < 24; ch++)
                a24[ch] = cbuf[(size_t)ch * CBS + tid] + conv_b[ch];

            const float scale = aff_scale[0] + 1e-8f;
            const float* confb = confidence + (size_t)b * H_ * W_;

            float dyv[8], dxv[8], av[8];
            float ssum = 0.f;
            #pragma unroll
            for (int j = 0; j < 8; j++) {
                float dy = a24[j];
                float dx = a24[8 + j];
                float a = tanhf(a24[16 + j]) / scale;
                float conf = bilin_zero(confb, (float)h + dy, (float)w + dx);
                a *= conf;
                dyv[j] = dy; dxv[j] = dx; av[j] = a;
                ssum += fabsf(a);
            }
            float s = fmaxf(ssum + 1e-4f, 1.0f);
            float inv_s = 1.0f / s;
            float suma = 0.f;
            #pragma unroll
            for (int j = 0; j < 8; j++) { av[j] *= inv_s; suma += av[j]; }
            const float aref = 1.0f - suma;

            const int hw = h * W_ + w;
            #pragma unroll
            for (int k = 0; k < 9; k++) {
                float dy = (k == 4) ? 0.f : dyv[(k < 4) ? k : k - 1];
                float dx = (k == 4) ? 0.f : dxv[(k < 4) ? k : k - 1];
                float a  = (k == 4) ? aref : av[(k < 4) ? k : k - 1];
                out_offset[((size_t)(b * 18 + 2 * k) * H_) * W_ + hw] = dy;
                out_offset[((size_t)(b * 18 + 2 * k + 1) * H_) * W_ + hw] = dx;
                out_aff9[((size_t)(b * 9 + k) * H_) * W_ + hw] = a;
            }

            const size_t pix = (size_t)b * H_ * W_ + hw;
            float ff = feat_fix[pix];
            float fi = feat_init[pix];
            float m = (ff > 0.f) ? 1.f : 0.f;
            fb0[pix] = (1.f - m) * fi + m * ff;
        }
    }
}

// One propagation step. do_blend=1 for iters 0..4, 0 for the final (raw sum -> d_out).
__global__ __launch_bounds__(256) void prop_kernel(
    const float* __restrict__ fb_in, const float* __restrict__ offset,
    const float* __restrict__ aff9, const float* __restrict__ feat_fix,
    float* __restrict__ out, int do_blend)
{
    const int idx = blockIdx.x * 256 + threadIdx.x;
    const int n = B_ * H_ * W_;
    if (idx >= n) return;
    const int w = idx % W_;
    const int h = (idx / W_) % H_;
    const int b = idx / (W_ * H_);
    const float* fbb = fb_in + (size_t)b * H_ * W_;
    const int hw = h * W_ + w;

    float sum = 0.f;
    #pragma unroll
    for (int k = 0; k < 9; k++) {
        float dy = offset[((size_t)(b * 18 + 2 * k) * H_) * W_ + hw];
        float dx = offset[((size_t)(b * 18 + 2 * k + 1) * H_) * W_ + hw];
        float a  = aff9[((size_t)(b * 9 + k) * H_) * W_ + hw];
        float y = (float)h + (float)(k / 3 - 1) + dy;
        float x = (float)w + (float)(k % 3 - 1) + dx;
        sum += a * bilin_zero(fbb, y, x);
    }
    if (do_blend) {
        float ff = feat_fix[idx];
        float m = (ff > 0.f) ? 1.f : 0.f;
        sum = (1.f - m) * sum + m * ff;
    }
    out[idx] = sum;
}

extern "C" void kernel_launch(void* const* d_in, const int* in_sizes, int n_in,
                              void* d_out, int out_size, void* d_ws, size_t ws_size,
                              hipStream_t stream) {
    const float* feat_init  = (const float*)d_in[0];
    const float* guidance   = (const float*)d_in[1];
    const float* confidence = (const float*)d_in[2];
    const float* feat_fix   = (const float*)d_in[3];
    const float* conv_w     = (const float*)d_in[4];
    const float* conv_b     = (const float*)d_in[5];
    const float* aff_scale  = (const float*)d_in[6];

    float* out_feat = (float*)d_out;                       // [B][1][H][W]
    const size_t P1 = (size_t)B_ * H_ * W_;
    float* out_offset = out_feat + P1;                     // [B][18][H][W]
    float* out_aff9   = out_offset + 18 * P1;              // [B][9][H][W]

    float* fb0 = (float*)d_ws;
    float* fb1 = fb0 + P1;
    __hip_bfloat16* wbf = (__hip_bfloat16*)(fb1 + P1);     // 32*576 bf16 = 36 KB

    repack_w_kernel<<<(32 * NUMK + 255) / 256, 256, 0, stream>>>(conv_w, wbf);

    conv_mfma_kernel<<<NBLK, 256, 0, stream>>>(
        guidance, wbf, conv_b, confidence, feat_init, feat_fix, aff_scale,
        out_offset, out_aff9, fb0);

    const int n = B_ * H_ * W_;
    const int pblocks = (n + 255) / 256;
    float* bufs[2] = {fb0, fb1};
    for (int it = 0; it < 6; it++) {
        const float* in = bufs[it & 1];
        float* o = (it == 5) ? out_feat : bufs[(it + 1) & 1];
        prop_kernel<<<pblocks, 256, 0, stream>>>(
            in, out_offset, out_aff9, feat_fix, o, (it < 5) ? 1 : 0);
    }
}

// Round 4
// 907.855 us; speedup vs baseline: 3.5566x; 1.3113x over previous
//
#include <hip/hip_runtime.h>
#include <hip/hip_bf16.h>
#include <math.h>

#define B_ 4
#define CG_ 64
#define H_ 240
#define W_ 1216
#define NUMK 576            // 9 taps * 64 ch
#define TW 64               // output pixels per block; 1216 = 19*64
#define NWT 19
#define LW 72               // staged cols [w0-4, w0+68)
#define CPAD 72             // channel stride in LDS bf16 (144 B rows, 16B-aligned)
#define NBLK (NWT * H_ * B_)   // 18240, %8==0 -> bijective XCD swizzle
#define CBS 68              // epilogue cbuf pixel stride (f32)

typedef __attribute__((ext_vector_type(8))) short bf16x8;
typedef __attribute__((ext_vector_type(4))) float f32x4;

// Bilinear sample with zero padding, per-corner validity (matches mmcv/ref).
__device__ __forceinline__ float bilin_zero(const float* __restrict__ img, float y, float x) {
    float y0f = floorf(y), x0f = floorf(x);
    float wy = y - y0f, wx = x - x0f;
    int y0 = (int)y0f, x0 = (int)x0f;
    int y1 = y0 + 1, x1 = x0 + 1;
    bool yv0 = ((unsigned)y0 < (unsigned)H_);
    bool yv1 = ((unsigned)y1 < (unsigned)H_);
    bool xv0 = ((unsigned)x0 < (unsigned)W_);
    bool xv1 = ((unsigned)x1 < (unsigned)W_);
    float v00 = (yv0 && xv0) ? img[y0 * W_ + x0] : 0.f;
    float v01 = (yv0 && xv1) ? img[y0 * W_ + x1] : 0.f;
    float v10 = (yv1 && xv0) ? img[y1 * W_ + x0] : 0.f;
    float v11 = (yv1 && xv1) ? img[y1 * W_ + x1] : 0.f;
    return v00 * (1.f - wy) * (1.f - wx) + v01 * (1.f - wy) * wx
         + v10 * wy * (1.f - wx) + v11 * wy * wx;
}

// Repack conv_w [24][64][3][3] (k = c*9+tap) -> wbf [32][576] bf16 with k' = tap*64+c.
__global__ __launch_bounds__(256) void repack_w_kernel(
    const float* __restrict__ conv_w, __hip_bfloat16* __restrict__ wbf)
{
    int i = blockIdx.x * 256 + threadIdx.x;
    if (i >= 32 * NUMK) return;
    int m = i / NUMK, k = i % NUMK;
    int tap = k / 64, c = k % 64;
    float v = (m < 24) ? conv_w[m * NUMK + c * 9 + tap] : 0.f;
    wbf[i] = __float2bfloat16(v);
}

// Implicit-GEMM conv (MFMA bf16) + offset/affinity prep + initial blend.
// LDS layout: [ky][col][CPAD] bf16 (col-major over channels, b128 fragment reads).
__global__ __launch_bounds__(256, 4) void conv_mfma_kernel(
    const float* __restrict__ guidance, const __hip_bfloat16* __restrict__ wbf,
    const float* __restrict__ conv_b, const float* __restrict__ confidence,
    const float* __restrict__ feat_init, const float* __restrict__ feat_fix,
    const float* __restrict__ aff_scale,
    float* __restrict__ out_offset,   // [B][18][H][W]
    float* __restrict__ out_aff9,     // [B][9][H][W]
    float* __restrict__ fb0)          // [B][H][W]
{
    __shared__ __align__(16) __hip_bfloat16 gl[3 * LW * CPAD];   // 31104 B; reused as cbuf

    const int tid = threadIdx.x;

    // XCD-bijective swizzle, h-fastest within each XCD chunk (row reuse in L2).
    int lin = (blockIdx.x & 7) * (NBLK / 8) + (blockIdx.x >> 3);
    const int h  = lin % H_;
    const int t  = lin / H_;
    const int wt = t % NWT;
    const int b  = t / NWT;
    const int w0 = wt * TW;

    // ---- stage guidance rows h-1..h+1, cols [w0-4, w0+68), 64 ch, bf16 ----
    // item i: col = i%72, ky = (i/72)%3, c4 = i/216; loads 4 channels at one col.
    // 3456 items = 13*256 + 128; fully unrolled for load pipelining.
    {
        auto stage_one = [&](int i) {
            int col = i % LW;
            int rest = i / LW;
            int ky = rest % 3;
            int c4 = rest / 3;
            int gh = h - 1 + ky;
            int gw = w0 - 4 + col;
            bool vok = ((unsigned)gh < (unsigned)H_) & ((unsigned)gw < (unsigned)W_);
            union { unsigned long long u; __hip_bfloat16 hv[4]; } pk;
            const float* src = guidance + (((size_t)b * CG_ + c4 * 4) * H_ + gh) * W_ + gw;
            #pragma unroll
            for (int j = 0; j < 4; j++) {
                float v = vok ? src[(size_t)j * H_ * W_] : 0.f;
                pk.hv[j] = __float2bfloat16(v);
            }
            *(unsigned long long*)&gl[(size_t)(ky * LW + col) * CPAD + c4 * 4] = pk.u;
        };
        #pragma unroll
        for (int it = 0; it < 13; it++)
            stage_one(tid + it * 256);
        if (tid < 3456 - 13 * 256)
            stage_one(tid + 13 * 256);
    }
    __syncthreads();

    // ---- MFMA K-loop: K = 576 = 18 steps of 32. k' = tap*64 + c. ----
    const int lane = tid & 63;
    const int wid  = tid >> 6;       // wave 0..3 -> pixels wid*16 .. +15
    const int p    = lane & 15;
    const int g    = lane >> 4;

    f32x4 acc[2] = {};               // two 16-row M tiles (out-ch 0-15, 16-31)

    #pragma unroll
    for (int s = 0; s < 18; s++) {
        const int tap = s >> 1;
        const int ky = tap / 3, kx = tap % 3;
        const int c0 = (s & 1) * 32;
        const __hip_bfloat16* wp = wbf + s * 32 + g * 8;
        bf16x8 a0 = *(const bf16x8*)(wp + (size_t)p * NUMK);
        bf16x8 a1 = *(const bf16x8*)(wp + (size_t)(16 + p) * NUMK);
        // B fragment: 8 contiguous channels c0+g*8 at staged col (sample w0+px+kx-1).
        int cb = 3 + wid * 16 + kx + p;     // (w0+px+kx-1) - (w0-4)
        bf16x8 b0 = *(const bf16x8*)(gl + (size_t)(ky * LW + cb) * CPAD + c0 + g * 8);
        acc[0] = __builtin_amdgcn_mfma_f32_16x16x32_bf16(a0, b0, acc[0], 0, 0, 0);
        acc[1] = __builtin_amdgcn_mfma_f32_16x16x32_bf16(a1, b0, acc[1], 0, 0, 0);
    }
    __syncthreads();   // all waves done reading gl

    // ---- spill conv result: cbuf[ch][px], ch<24, px<64 ----
    float* cbuf = (float*)gl;
    #pragma unroll
    for (int mt = 0; mt < 2; mt++) {
        int ch = mt * 16 + g * 4;
        if (ch < 24) {
            int px = wid * 16 + p;
            #pragma unroll
            for (int r = 0; r < 4; r++)
                cbuf[(size_t)(ch + r) * CBS + px] = acc[mt][r];
        }
    }
    __syncthreads();

    // ---- prep epilogue: threads 0..63 = pixels ----
    if (tid < TW) {
        const int w = w0 + tid;
        float a24[24];
        #pragma unroll
        for (int ch = 0; ch < 24; ch++)
            a24[ch] = cbuf[(size_t)ch * CBS + tid] + conv_b[ch];

        const float scale = aff_scale[0] + 1e-8f;
        const float* confb = confidence + (size_t)b * H_ * W_;

        float dyv[8], dxv[8], av[8];
        float ssum = 0.f;
        #pragma unroll
        for (int j = 0; j < 8; j++) {
            float dy = a24[j];
            float dx = a24[8 + j];
            float a = tanhf(a24[16 + j]) / scale;
            float conf = bilin_zero(confb, (float)h + dy, (float)w + dx);
            a *= conf;
            dyv[j] = dy; dxv[j] = dx; av[j] = a;
            ssum += fabsf(a);
        }
        float s = fmaxf(ssum + 1e-4f, 1.0f);
        float inv_s = 1.0f / s;
        float suma = 0.f;
        #pragma unroll
        for (int j = 0; j < 8; j++) { av[j] *= inv_s; suma += av[j]; }
        const float aref = 1.0f - suma;

        const int hw = h * W_ + w;
        #pragma unroll
        for (int k = 0; k < 9; k++) {
            float dy = (k == 4) ? 0.f : dyv[(k < 4) ? k : k - 1];
            float dx = (k == 4) ? 0.f : dxv[(k < 4) ? k : k - 1];
            float a  = (k == 4) ? aref : av[(k < 4) ? k : k - 1];
            out_offset[((size_t)(b * 18 + 2 * k) * H_) * W_ + hw] = dy;
            out_offset[((size_t)(b * 18 + 2 * k + 1) * H_) * W_ + hw] = dx;
            out_aff9[((size_t)(b * 9 + k) * H_) * W_ + hw] = a;
        }

        const size_t pix = (size_t)b * H_ * W_ + hw;
        float ff = feat_fix[pix];
        float fi = feat_init[pix];
        float m = (ff > 0.f) ? 1.f : 0.f;
        fb0[pix] = (1.f - m) * fi + m * ff;
    }
}

// One propagation step. do_blend=1 for iters 0..4, 0 for the final (raw sum -> d_out).
__global__ __launch_bounds__(256) void prop_kernel(
    const float* __restrict__ fb_in, const float* __restrict__ offset,
    const float* __restrict__ aff9, const float* __restrict__ feat_fix,
    float* __restrict__ out, int do_blend)
{
    const int idx = blockIdx.x * 256 + threadIdx.x;
    const int n = B_ * H_ * W_;
    if (idx >= n) return;
    const int w = idx % W_;
    const int h = (idx / W_) % H_;
    const int b = idx / (W_ * H_);
    const float* fbb = fb_in + (size_t)b * H_ * W_;
    const int hw = h * W_ + w;

    float sum = 0.f;
    #pragma unroll
    for (int k = 0; k < 9; k++) {
        float dy = offset[((size_t)(b * 18 + 2 * k) * H_) * W_ + hw];
        float dx = offset[((size_t)(b * 18 + 2 * k + 1) * H_) * W_ + hw];
        float a  = aff9[((size_t)(b * 9 + k) * H_) * W_ + hw];
        float y = (float)h + (float)(k / 3 - 1) + dy;
        float x = (float)w + (float)(k % 3 - 1) + dx;
        sum += a * bilin_zero(fbb, y, x);
    }
    if (do_blend) {
        float ff = feat_fix[idx];
        float m = (ff > 0.f) ? 1.f : 0.f;
        sum = (1.f - m) * sum + m * ff;
    }
    out[idx] = sum;
}

extern "C" void kernel_launch(void* const* d_in, const int* in_sizes, int n_in,
                              void* d_out, int out_size, void* d_ws, size_t ws_size,
                              hipStream_t stream) {
    const float* feat_init  = (const float*)d_in[0];
    const float* guidance   = (const float*)d_in[1];
    const float* confidence = (const float*)d_in[2];
    const float* feat_fix   = (const float*)d_in[3];
    const float* conv_w     = (const float*)d_in[4];
    const float* conv_b     = (const float*)d_in[5];
    const float* aff_scale  = (const float*)d_in[6];

    float* out_feat = (float*)d_out;                       // [B][1][H][W]
    const size_t P1 = (size_t)B_ * H_ * W_;
    float* out_offset = out_feat + P1;                     // [B][18][H][W]
    float* out_aff9   = out_offset + 18 * P1;              // [B][9][H][W]

    float* fb0 = (float*)d_ws;
    float* fb1 = fb0 + P1;
    __hip_bfloat16* wbf = (__hip_bfloat16*)(fb1 + P1);     // 32*576 bf16 = 36 KB

    repack_w_kernel<<<(32 * NUMK + 255) / 256, 256, 0, stream>>>(conv_w, wbf);

    conv_mfma_kernel<<<NBLK, 256, 0, stream>>>(
        guidance, wbf, conv_b, confidence, feat_init, feat_fix, aff_scale,
        out_offset, out_aff9, fb0);

    const int n = B_ * H_ * W_;
    const int pblocks = (n + 255) / 256;
    float* bufs[2] = {fb0, fb1};
    for (int it = 0; it < 6; it++) {
        const float* in = bufs[it & 1];
        float* o = (it == 5) ? out_feat : bufs[(it + 1) & 1];
        prop_kernel<<<pblocks, 256, 0, stream>>>(
            in, out_offset, out_aff9, feat_fix, o, (it < 5) ? 1 : 0);
    }
}

// Round 5
// 628.890 us; speedup vs baseline: 5.1343x; 1.4436x over previous
//
#include <hip/hip_runtime.h>
#include <hip/hip_bf16.h>
#include <math.h>

#define B_ 4
#define CG_ 64
#define H_ 240
#define W_ 1216
#define NUMK 576            // 9 taps * 64 ch
#define TC 16               // output cols per block
#define TH 4                // output rows per block (one per wave)
#define SC 20               // staged cols [w0-2, w0+18)
#define SR 6                // staged rows h0-1 .. h0+4
#define CPAD 72             // channel stride in LDS bf16 (144 B rows)
#define NWT (W_ / TC)       // 76
#define NHT (H_ / TH)       // 60
#define NBLK (NWT * NHT * B_)   // 18240, %8==0 -> bijective XCD swizzle
#define CBS 68              // epilogue cbuf pixel stride (f32)

typedef __attribute__((ext_vector_type(8))) short bf16x8;
typedef __attribute__((ext_vector_type(4))) float f32x4;

// Bilinear sample with zero padding, per-corner validity (matches mmcv/ref).
__device__ __forceinline__ float bilin_zero(const float* __restrict__ img, float y, float x) {
    float y0f = floorf(y), x0f = floorf(x);
    float wy = y - y0f, wx = x - x0f;
    int y0 = (int)y0f, x0 = (int)x0f;
    int y1 = y0 + 1, x1 = x0 + 1;
    bool yv0 = ((unsigned)y0 < (unsigned)H_);
    bool yv1 = ((unsigned)y1 < (unsigned)H_);
    bool xv0 = ((unsigned)x0 < (unsigned)W_);
    bool xv1 = ((unsigned)x1 < (unsigned)W_);
    float v00 = (yv0 && xv0) ? img[y0 * W_ + x0] : 0.f;
    float v01 = (yv0 && xv1) ? img[y0 * W_ + x1] : 0.f;
    float v10 = (yv1 && xv0) ? img[y1 * W_ + x0] : 0.f;
    float v11 = (yv1 && xv1) ? img[y1 * W_ + x1] : 0.f;
    return v00 * (1.f - wy) * (1.f - wx) + v01 * (1.f - wy) * wx
         + v10 * wy * (1.f - wx) + v11 * wy * wx;
}

// Repack conv_w [24][64][3][3] into fragment-major bf16:
// wfrag[((s*8 + half*4 + g)*16 + p)*8 + e] = W[m = half*16+p][k' = s*32+g*8+e]
// with k' = tap*64 + c (tap = k'/64, c = k'%64); rows m>=24 are zero.
// Each in-kernel A-fragment load is then a wave-contiguous 1 KB read.
__global__ __launch_bounds__(256) void repack_w_kernel(
    const float* __restrict__ conv_w, __hip_bfloat16* __restrict__ wfrag)
{
    int i = blockIdx.x * 256 + threadIdx.x;
    if (i >= 32 * NUMK) return;
    int e = i & 7;
    int p = (i >> 3) & 15;
    int g = (i >> 7) & 3;
    int half = (i >> 9) & 1;
    int s = i >> 10;
    int m = half * 16 + p;
    int kp = s * 32 + g * 8 + e;
    int tap = kp / 64, c = kp % 64;
    float v = (m < 24) ? conv_w[m * NUMK + c * 9 + tap] : 0.f;
    wfrag[i] = __float2bfloat16(v);
}

// Implicit-GEMM conv (MFMA bf16) + offset/affinity prep + initial blend.
// Tile: 16 cols x 4 rows; LDS [SR][SC][CPAD] bf16, channel-contiguous b128 reads.
__global__ __launch_bounds__(256, 8) void conv_mfma_kernel(
    const float* __restrict__ guidance, const __hip_bfloat16* __restrict__ wfrag,
    const float* __restrict__ conv_b, const float* __restrict__ confidence,
    const float* __restrict__ feat_init, const float* __restrict__ feat_fix,
    const float* __restrict__ aff_scale,
    float* __restrict__ out_offset,   // [B][18][H][W]
    float* __restrict__ out_aff9,     // [B][9][H][W]
    float* __restrict__ fb0)          // [B][H][W]
{
    __shared__ __align__(16) __hip_bfloat16 gl[SR * SC * CPAD];   // 17280 B; reused as cbuf

    const int tid = threadIdx.x;

    // XCD-bijective swizzle, row-tile fastest (vertical halo reuse within XCD L2).
    int lin = (blockIdx.x & 7) * (NBLK / 8) + (blockIdx.x >> 3);
    const int r0 = lin % NHT;
    const int rest = lin / NHT;
    const int wt = rest % NWT;
    const int b  = rest / NWT;
    const int h0 = r0 * TH;
    const int w0 = wt * TC;

    // ---- stage guidance rows h0-1..h0+4, cols [w0-2, w0+18), 64 ch, bf16 ----
    // item i: col = i%20, kr = (i/20)%6, c4 = i/120; 1920 items = 7*256 + 128.
    {
        auto stage_one = [&](int i) {
            int col = i % SC;
            int rest2 = i / SC;
            int kr = rest2 % SR;
            int c4 = rest2 / SR;
            int gh = h0 - 1 + kr;
            int gw = w0 - 2 + col;
            bool vok = ((unsigned)gh < (unsigned)H_) & ((unsigned)gw < (unsigned)W_);
            union { unsigned long long u; __hip_bfloat16 hv[4]; } pk;
            const float* src = guidance + (((size_t)b * CG_ + c4 * 4) * H_ + gh) * W_ + gw;
            #pragma unroll
            for (int j = 0; j < 4; j++) {
                float v = vok ? src[(size_t)j * H_ * W_] : 0.f;
                pk.hv[j] = __float2bfloat16(v);
            }
            *(unsigned long long*)&gl[(size_t)(kr * SC + col) * CPAD + c4 * 4] = pk.u;
        };
        #pragma unroll
        for (int it = 0; it < 7; it++)
            stage_one(tid + it * 256);
        if (tid < SR * SC * 16 - 7 * 256)
            stage_one(tid + 7 * 256);
    }
    __syncthreads();

    // ---- MFMA K-loop: K = 576 = 18 steps of 32. k' = tap*64 + c. ----
    const int lane = tid & 63;
    const int wid  = tid >> 6;       // wave = output row r = wid
    const int p    = lane & 15;
    const int g    = lane >> 4;

    f32x4 acc[2] = {};               // two 16-row M tiles (out-ch 0-15, 16-31)

    #pragma unroll
    for (int s = 0; s < 18; s++) {
        const int tap = s >> 1;
        const int ky = tap / 3, kx = tap % 3;
        const int c0 = (s & 1) * 32;
        // A fragments: wave-contiguous 1 KB reads from fragment-major wfrag.
        const __hip_bfloat16* wp = wfrag + (size_t)s * 1024 + g * 128 + p * 8;
        bf16x8 a0 = *(const bf16x8*)(wp);
        bf16x8 a1 = *(const bf16x8*)(wp + 512);
        // B fragment: 8 contiguous channels c0+g*8, row wid+ky, col (w0+p+kx-1).
        int cb = p + kx + 1;         // (w0+p+kx-1) - (w0-2)
        bf16x8 b0 = *(const bf16x8*)(gl + (size_t)((wid + ky) * SC + cb) * CPAD + c0 + g * 8);
        acc[0] = __builtin_amdgcn_mfma_f32_16x16x32_bf16(a0, b0, acc[0], 0, 0, 0);
        acc[1] = __builtin_amdgcn_mfma_f32_16x16x32_bf16(a1, b0, acc[1], 0, 0, 0);
    }
    __syncthreads();   // all waves done reading gl

    // ---- spill conv result: cbuf[ch][px], ch<24, px = wid*16 + p ----
    float* cbuf = (float*)gl;
    #pragma unroll
    for (int mt = 0; mt < 2; mt++) {
        int ch = mt * 16 + g * 4;
        if (ch < 24) {
            int px = wid * 16 + p;
            #pragma unroll
            for (int r = 0; r < 4; r++)
                cbuf[(size_t)(ch + r) * CBS + px] = acc[mt][r];
        }
    }
    __syncthreads();

    // ---- prep epilogue: threads 0..63 -> px tid = (row tid/16, col tid%16) ----
    if (tid < TH * TC) {
        const int h = h0 + (tid >> 4);
        const int w = w0 + (tid & 15);
        float a24[24];
        #pragma unroll
        for (int ch = 0; ch < 24; ch++)
            a24[ch] = cbuf[(size_t)ch * CBS + tid] + conv_b[ch];

        const float scale = aff_scale[0] + 1e-8f;
        const float* confb = confidence + (size_t)b * H_ * W_;

        float dyv[8], dxv[8], av[8];
        float ssum = 0.f;
        #pragma unroll
        for (int j = 0; j < 8; j++) {
            float dy = a24[j];
            float dx = a24[8 + j];
            float a = tanhf(a24[16 + j]) / scale;
            float conf = bilin_zero(confb, (float)h + dy, (float)w + dx);
            a *= conf;
            dyv[j] = dy; dxv[j] = dx; av[j] = a;
            ssum += fabsf(a);
        }
        float s = fmaxf(ssum + 1e-4f, 1.0f);
        float inv_s = 1.0f / s;
        float suma = 0.f;
        #pragma unroll
        for (int j = 0; j < 8; j++) { av[j] *= inv_s; suma += av[j]; }
        const float aref = 1.0f - suma;

        const int hw = h * W_ + w;
        #pragma unroll
        for (int k = 0; k < 9; k++) {
            float dy = (k == 4) ? 0.f : dyv[(k < 4) ? k : k - 1];
            float dx = (k == 4) ? 0.f : dxv[(k < 4) ? k : k - 1];
            float a  = (k == 4) ? aref : av[(k < 4) ? k : k - 1];
            out_offset[((size_t)(b * 18 + 2 * k) * H_) * W_ + hw] = dy;
            out_offset[((size_t)(b * 18 + 2 * k + 1) * H_) * W_ + hw] = dx;
            out_aff9[((size_t)(b * 9 + k) * H_) * W_ + hw] = a;
        }

        const size_t pix = (size_t)b * H_ * W_ + hw;
        float ff = feat_fix[pix];
        float fi = feat_init[pix];
        float m = (ff > 0.f) ? 1.f : 0.f;
        fb0[pix] = (1.f - m) * fi + m * ff;
    }
}

// One propagation step. do_blend=1 for iters 0..4, 0 for the final (raw sum -> d_out).
__global__ __launch_bounds__(256) void prop_kernel(
    const float* __restrict__ fb_in, const float* __restrict__ offset,
    const float* __restrict__ aff9, const float* __restrict__ feat_fix,
    float* __restrict__ out, int do_blend)
{
    const int idx = blockIdx.x * 256 + threadIdx.x;
    const int n = B_ * H_ * W_;
    if (idx >= n) return;
    const int w = idx % W_;
    const int h = (idx / W_) % H_;
    const int b = idx / (W_ * H_);
    const float* fbb = fb_in + (size_t)b * H_ * W_;
    const int hw = h * W_ + w;

    float sum = 0.f;
    #pragma unroll
    for (int k = 0; k < 9; k++) {
        float dy = offset[((size_t)(b * 18 + 2 * k) * H_) * W_ + hw];
        float dx = offset[((size_t)(b * 18 + 2 * k + 1) * H_) * W_ + hw];
        float a  = aff9[((size_t)(b * 9 + k) * H_) * W_ + hw];
        float y = (float)h + (float)(k / 3 - 1) + dy;
        float x = (float)w + (float)(k % 3 - 1) + dx;
        sum += a * bilin_zero(fbb, y, x);
    }
    if (do_blend) {
        float ff = feat_fix[idx];
        float m = (ff > 0.f) ? 1.f : 0.f;
        sum = (1.f - m) * sum + m * ff;
    }
    out[idx] = sum;
}

extern "C" void kernel_launch(void* const* d_in, const int* in_sizes, int n_in,
                              void* d_out, int out_size, void* d_ws, size_t ws_size,
                              hipStream_t stream) {
    const float* feat_init  = (const float*)d_in[0];
    const float* guidance   = (const float*)d_in[1];
    const float* confidence = (const float*)d_in[2];
    const float* feat_fix   = (const float*)d_in[3];
    const float* conv_w     = (const float*)d_in[4];
    const float* conv_b     = (const float*)d_in[5];
    const float* aff_scale  = (const float*)d_in[6];

    float* out_feat = (float*)d_out;                       // [B][1][H][W]
    const size_t P1 = (size_t)B_ * H_ * W_;
    float* out_offset = out_feat + P1;                     // [B][18][H][W]
    float* out_aff9   = out_offset + 18 * P1;              // [B][9][H][W]

    float* fb0 = (float*)d_ws;
    float* fb1 = fb0 + P1;
    __hip_bfloat16* wfrag = (__hip_bfloat16*)(fb1 + P1);   // 32*576 bf16 = 36 KB

    repack_w_kernel<<<(32 * NUMK + 255) / 256, 256, 0, stream>>>(conv_w, wfrag);

    conv_mfma_kernel<<<NBLK, 256, 0, stream>>>(
        guidance, wfrag, conv_b, confidence, feat_init, feat_fix, aff_scale,
        out_offset, out_aff9, fb0);

    const int n = B_ * H_ * W_;
    const int pblocks = (n + 255) / 256;
    float* bufs[2] = {fb0, fb1};
    for (int it = 0; it < 6; it++) {
        const float* in = bufs[it & 1];
        float* o = (it == 5) ? out_feat : bufs[(it + 1) & 1];
        prop_kernel<<<pblocks, 256, 0, stream>>>(
            in, out_offset, out_aff9, feat_fix, o, (it < 5) ? 1 : 0);
    }
}